// Round 1
// baseline (234.938 us; speedup 1.0000x reference)
//
#include <hip/hip_runtime.h>

// LIF scan: mem[t] = beta*mem[t-1] + x[t]; spk = (mem >= thresh); mem *= (1-spk).
// x layout [T=8, N=4194304] time-major; recurrence per-neuron only -> one thread
// owns 4 neurons (float4) and scans T=8 in registers. Memory-bound: 256 MiB total
// traffic, roofline ~43 us at 6.3 TB/s.

#define LIF_THRESH 0.5f
#define LIF_BETA   0.25f
#define LIF_T      8

__global__ __launch_bounds__(256) void lif_kernel(const float4* __restrict__ x,
                                                  float4* __restrict__ out,
                                                  int n4) {
    int i = blockIdx.x * blockDim.x + threadIdx.x;
    if (i >= n4) return;

    // Issue all T loads up front: addresses are independent of the recurrence,
    // so the wave gets 8 outstanding global_load_dwordx4 (MLP) before any waitcnt.
    float4 xv[LIF_T];
#pragma unroll
    for (int t = 0; t < LIF_T; ++t) {
        xv[t] = x[(size_t)t * n4 + i];
    }

    float mx = 0.f, my = 0.f, mz = 0.f, mw = 0.f;
#pragma unroll
    for (int t = 0; t < LIF_T; ++t) {
        float4 xt = xv[t];
        mx = mx * LIF_BETA + xt.x;
        my = my * LIF_BETA + xt.y;
        mz = mz * LIF_BETA + xt.z;
        mw = mw * LIF_BETA + xt.w;

        float4 s;
        s.x = (mx >= LIF_THRESH) ? 1.f : 0.f;
        s.y = (my >= LIF_THRESH) ? 1.f : 0.f;
        s.z = (mz >= LIF_THRESH) ? 1.f : 0.f;
        s.w = (mw >= LIF_THRESH) ? 1.f : 0.f;

        // hard reset
        mx = (mx >= LIF_THRESH) ? 0.f : mx;
        my = (my >= LIF_THRESH) ? 0.f : my;
        mz = (mz >= LIF_THRESH) ? 0.f : mz;
        mw = (mw >= LIF_THRESH) ? 0.f : mw;

        out[(size_t)t * n4 + i] = s;
    }
}

extern "C" void kernel_launch(void* const* d_in, const int* in_sizes, int n_in,
                              void* d_out, int out_size, void* d_ws, size_t ws_size,
                              hipStream_t stream) {
    const float* x = (const float*)d_in[0];
    float* out = (float*)d_out;

    // in_sizes[0] = T*N total elements; per-timestep N = total / T.
    long long total = in_sizes[0];
    int n = (int)(total / LIF_T);     // 4,194,304 floats per timestep
    int n4 = n / 4;                   // 1,048,576 float4 per timestep

    dim3 block(256);
    dim3 grid((n4 + 255) / 256);
    lif_kernel<<<grid, block, 0, stream>>>((const float4*)x, (float4*)out, n4);
}